// Round 8
// baseline (455.550 us; speedup 1.0000x reference)
//
#include <hip/hip_runtime.h>
#include <hip/hip_bf16.h>
#include <math.h>

#define TT 512
#define NN 200
#define HH 64
#define EE 16
#define RR 10
#define MU_OFF 0
#define COV_OFF (TT*NN)      // 102400
#define HBLK (NN*NN)         // 40000 floats per t-block of cov
#define HPAD 68              // padded hist row

__device__ __forceinline__ float sigmoidf_(float x) {
    return 1.0f / (1.0f + __expf(-x));
}
__device__ __forceinline__ float tanhf_(float x) {
    x = fminf(15.0f, fmaxf(-15.0f, x));
    float e = __expf(2.0f * x);
    return (e - 1.0f) / (e + 1.0f);
}
// unified gate activation: sigmoid(g) or tanh(g)=2*sigmoid(2g)-1
__device__ __forceinline__ float act_(float g, bool is_tanh) {
    float xx = is_tanh ? 2.0f * g : g;
    float e = __expf(-xx);
    float v = 1.0f / (1.0f + e);
    return is_tanh ? fmaf(2.0f, v, -1.0f) : v;
}

// quad_perm DPP xor-swaps (VALU pipe, not LDS pipe)
__device__ __forceinline__ float dppxor1(float v) {   // lanes [1,0,3,2]
    return __int_as_float(__builtin_amdgcn_mov_dpp(__float_as_int(v), 0xB1, 0xf, 0xf, true));
}
__device__ __forceinline__ float dppxor2(float v) {   // lanes [2,3,0,1]
    return __int_as_float(__builtin_amdgcn_mov_dpp(__float_as_int(v), 0x4E, 0xf, 0xf, true));
}

// Raw wave-counted barrier: waits LDS only (lgkmcnt), never drains vmcnt.
#define BAR() do { asm volatile("s_waitcnt lgkmcnt(0)" ::: "memory"); \
                   __builtin_amdgcn_s_barrier();                      \
                   asm volatile("" ::: "memory"); } while (0)

#define PIN4(v) asm volatile("" : "+v"(v.x), "+v"(v.y), "+v"(v.z), "+v"(v.w))
#define RM4(M) M(0) M(1) M(2) M(3)

// ---------------- Kernel A: 2-layer LSTM, 3-group layer-pipelined ----------
// 768 threads = 3 groups x 256, quad-split: each thread owns 4 rows x 16-k
// = exactly 64 weight floats (every group identical residency; R2-R7's
// 128-float branch was the over-pressure that forced AGPR shunting).
//   grp0 (waves 0-3):  layer0 gates, step t   (Whh0 + Wih0 scalar + bias, act)
//   grp1 (waves 4-7):  layer1 ih-partial, t-1 (Wih1 . h0, bias)
//   grp2 (waves 8-11): layer1 hh-partial, t-1 (Whh1 . h1)
// Update: wave0 -> c0/h0;  wave8 -> combine partials -> c1/h1.
__global__
__attribute__((amdgpu_flat_work_group_size(768, 768), amdgpu_waves_per_eu(3, 3)))
void lstm_kernel(
    const float* __restrict__ inputs,
    const float* __restrict__ Wih0, const float* __restrict__ Whh0,
    const float* __restrict__ bih0, const float* __restrict__ bhh0,
    const float* __restrict__ Wih1, const float* __restrict__ Whh1,
    const float* __restrict__ bih1, const float* __restrict__ bhh1,
    float* __restrict__ out)
{
    const int n   = blockIdx.x;
    const int tid = threadIdx.x;
    const int grp = tid >> 8;       // 0,1,2 (wave-uniform)
    const int r   = tid & 255;      // gate row within group
    const int b4  = r & ~3;         // first of this thread's 4 rows
    const int qr  = r & 3;          // k-quarter (16 floats)

    __shared__ float xs[TT];
    __shared__ float h0s[HH];
    __shared__ float h1s[HH];
    __shared__ float ga0[256];      // activated layer0 gates
    __shared__ float pih[256];      // layer1 ih partial (incl. bias)
    __shared__ float phh[256];      // layer1 hh partial
    __shared__ float hist[64][HPAD];

    // ---- per-thread weights: 4 rows x 16 k-floats, uniform across groups ---
    const float* wbase = (grp == 0) ? Whh0 : (grp == 1) ? Wih1 : Whh1;
#define DECLW(m) \
    float4 w##m##_0, w##m##_1, w##m##_2, w##m##_3; \
    { const float4* p = (const float4*)(wbase + (b4 + m) * HH + qr * 16); \
      w##m##_0 = p[0]; w##m##_1 = p[1]; w##m##_2 = p[2]; w##m##_3 = p[3]; \
      PIN4(w##m##_0); PIN4(w##m##_1); PIN4(w##m##_2); PIN4(w##m##_3); }
    RM4(DECLW)
#define DECLC(m) \
    const float wx##m = (grp == 0) ? Wih0[b4 + m] : 0.0f; \
    const float bb##m = (grp == 0) ? (bih0[b4 + m] + bhh0[b4 + m]) \
                       : (grp == 1) ? (bih1[b4 + m] + bhh1[b4 + m]) : 0.0f;
    RM4(DECLC)
    const bool is_t = ((r >> 6) == 2);   // gate-2 rows use tanh (wave-uniform)

    if (tid < TT) xs[tid] = inputs[tid * NN + n];
    if (tid < HH) { h0s[tid] = 0.0f; h1s[tid] = 0.0f; }
    float c0 = 0.0f;   // live in wave 0 (tid<64)
    float c1 = 0.0f;   // live in wave 8 (tid 512..575)
    __syncthreads();

    float* covbase = out + COV_OFF + n * HH;
    const float* src = (grp == 2) ? h1s : h0s;

    for (int t = 0; t <= TT; ++t) {
        // ---- compute phase: three matvec groups in parallel ----------------
        const bool active = (grp == 0) ? (t < TT) : (t >= 1);
        if (active) {
            const float x = xs[t & (TT - 1)];      // only used where wx != 0
            const float4* hq = (const float4*)(src + qr * 16);
            float4 hc0 = hq[0], hc1 = hq[1], hc2 = hq[2], hc3 = hq[3];
            float acc0, acc1, acc2, acc3;
#define MV(m) { \
            float a = (qr == 0) ? fmaf(wx##m, x, bb##m) : 0.0f; \
            a = fmaf(w##m##_0.x, hc0.x, a); \
            a = fmaf(w##m##_0.y, hc0.y, a); \
            a = fmaf(w##m##_0.z, hc0.z, a); \
            a = fmaf(w##m##_0.w, hc0.w, a); \
            a = fmaf(w##m##_1.x, hc1.x, a); \
            a = fmaf(w##m##_1.y, hc1.y, a); \
            a = fmaf(w##m##_1.z, hc1.z, a); \
            a = fmaf(w##m##_1.w, hc1.w, a); \
            a = fmaf(w##m##_2.x, hc2.x, a); \
            a = fmaf(w##m##_2.y, hc2.y, a); \
            a = fmaf(w##m##_2.z, hc2.z, a); \
            a = fmaf(w##m##_2.w, hc2.w, a); \
            a = fmaf(w##m##_3.x, hc3.x, a); \
            a = fmaf(w##m##_3.y, hc3.y, a); \
            a = fmaf(w##m##_3.z, hc3.z, a); \
            a = fmaf(w##m##_3.w, hc3.w, a); \
            acc##m = a; }
            RM4(MV)
            acc0 += dppxor1(acc0); acc0 += dppxor2(acc0);
            acc1 += dppxor1(acc1); acc1 += dppxor2(acc1);
            acc2 += dppxor1(acc2); acc2 += dppxor2(acc2);
            acc3 += dppxor1(acc3); acc3 += dppxor2(acc3);
            float g = (qr == 0) ? acc0 : (qr == 1) ? acc1 : (qr == 2) ? acc2 : acc3;
            if (grp == 0)      ga0[r] = act_(g, is_t);   // row == r
            else if (grp == 1) pih[r] = g;
            else               phh[r] = g;
        }
        BAR();

        // ---- update phase --------------------------------------------------
        if (tid < HH) {
            if (t < TT) {
                float ia = ga0[tid], fa = ga0[tid + 64];
                float gg = ga0[tid + 128], oa = ga0[tid + 192];
                c0 = fmaf(fa, c0, ia * gg);
                h0s[tid] = oa * tanhf_(c0);
            }
        } else if (tid >= 512 && tid < 512 + HH) {
            if (t >= 1) {
                const int j = tid - 512;
                float gi = pih[j]       + phh[j];
                float gf = pih[j + 64]  + phh[j + 64];
                float gg = pih[j + 128] + phh[j + 128];
                float go = pih[j + 192] + phh[j + 192];
                c1 = fmaf(sigmoidf_(gf), c1, sigmoidf_(gi) * tanhf_(gg));
                float h1 = sigmoidf_(go) * tanhf_(c1);
                h1s[j] = h1;
                hist[(t - 1) & 63][j] = h1;
            }
        }
        BAR();

        // ---- periodic h1-history flush (64 steps at a time) ---------------
        if ((t & 63) == 0 && t > 0 && tid < 512) {
            const int s = tid >> 3;          // step row 0..63
            const int c = (tid & 7) * 8;     // 8 floats per thread
            float4 v0 = *(const float4*)&hist[s][c];
            float4 v1 = *(const float4*)&hist[s][c + 4];
            float* dst = covbase + (size_t)(t - 64 + s) * HBLK + c;
            ((float4*)dst)[0] = v0;
            ((float4*)dst)[1] = v1;
        }
    }
}

// ---------------- Kernel B: heads + covariance, one workgroup per t ----------
__global__ __launch_bounds__(256) void head_kernel(
    const float* __restrict__ embW, const int* __restrict__ indices,
    const float* __restrict__ Wm, const float* __restrict__ bm,
    const float* __restrict__ Wv, const float* __restrict__ bv,
    const float* __restrict__ Wd, const float* __restrict__ bd,
    float* __restrict__ out)
{
    const int t = blockIdx.x;
    const int tid = threadIdx.x;

    __shared__ float hs[NN * HH];          // 12800
    __shared__ float embs[NN * EE];        // 3200
    __shared__ float Wvs[(HH + EE) * RR];  // 800
    __shared__ float Wms[HH + EE];
    __shared__ float Wds[HH + EE];
    __shared__ float Vs[NN * (RR + 1)];    // stride 11 to dodge bank conflicts
    __shared__ float dsh[NN];
    __shared__ float bvs[RR];

    const float* hsrc = out + COV_OFF + (size_t)t * HBLK;
    for (int i = tid; i < (NN * HH) / 4; i += 256)
        ((float4*)hs)[i] = ((const float4*)hsrc)[i];
    for (int i = tid; i < NN * EE; i += 256) {
        int n = i >> 4, e = i & 15;
        embs[i] = embW[indices[n] * EE + e];
    }
    for (int i = tid; i < (HH + EE) * RR; i += 256) Wvs[i] = Wv[i];
    if (tid < HH + EE) { Wms[tid] = Wm[tid]; Wds[tid] = Wd[tid]; }
    if (tid < RR) bvs[tid] = bv[tid];
    __syncthreads();

    // V = y @ Wv + bv
    for (int p = tid; p < NN * RR; p += 256) {
        int n = p / RR, r = p - n * RR;
        const float* hn = hs + n * HH;
        const float* en = embs + n * EE;
        float acc = bvs[r];
#pragma unroll 8
        for (int k = 0; k < HH; ++k) acc = fmaf(hn[k], Wvs[k * RR + r], acc);
#pragma unroll
        for (int k = 0; k < EE; ++k) acc = fmaf(en[k], Wvs[(HH + k) * RR + r], acc);
        Vs[n * (RR + 1) + r] = acc;
    }
    // mu and d
    const float bmv = bm[0], bdv = bd[0];
    for (int n = tid; n < NN; n += 256) {
        const float* hn = hs + n * HH;
        const float* en = embs + n * EE;
        float am = bmv, ad = bdv;
#pragma unroll 8
        for (int k = 0; k < HH; ++k) {
            float h = hn[k];
            am = fmaf(h, Wms[k], am);
            ad = fmaf(h, Wds[k], ad);
        }
#pragma unroll
        for (int k = 0; k < EE; ++k) {
            float e = en[k];
            am = fmaf(e, Wms[HH + k], am);
            ad = fmaf(e, Wds[HH + k], ad);
        }
        out[MU_OFF + t * NN + n] = am;
        dsh[n] = (ad > 20.0f) ? ad : log1pf(__expf(ad));  // softplus
    }
    __syncthreads();

    // cov[t] = V V^T + diag(d)  — overwrites the whole block (incl. stashed h)
    float* covp = out + COV_OFF + (size_t)t * HBLK;
    for (int p = tid; p < NN * NN; p += 256) {
        int n = p / NN, m = p - n * NN;
        const float* vn = Vs + n * (RR + 1);
        const float* vm = Vs + m * (RR + 1);
        float acc = (n == m) ? dsh[n] : 0.0f;
#pragma unroll
        for (int r = 0; r < RR; ++r) acc = fmaf(vn[r], vm[r], acc);
        covp[p] = acc;
    }
}

extern "C" void kernel_launch(void* const* d_in, const int* in_sizes, int n_in,
                              void* d_out, int out_size, void* d_ws, size_t ws_size,
                              hipStream_t stream) {
    const float* inputs  = (const float*)d_in[0];
    const int*   indices = (const int*)d_in[1];
    const float* embW    = (const float*)d_in[2];
    const float* Wih0    = (const float*)d_in[3];
    const float* Whh0    = (const float*)d_in[4];
    const float* bih0    = (const float*)d_in[5];
    const float* bhh0    = (const float*)d_in[6];
    const float* Wih1    = (const float*)d_in[7];
    const float* Whh1    = (const float*)d_in[8];
    const float* bih1    = (const float*)d_in[9];
    const float* bhh1    = (const float*)d_in[10];
    const float* Wm      = (const float*)d_in[11];
    const float* bm      = (const float*)d_in[12];
    const float* Wv      = (const float*)d_in[13];
    const float* bv      = (const float*)d_in[14];
    const float* Wd      = (const float*)d_in[15];
    const float* bd      = (const float*)d_in[16];
    float* out = (float*)d_out;

    lstm_kernel<<<NN, 768, 0, stream>>>(inputs, Wih0, Whh0, bih0, bhh0,
                                        Wih1, Whh1, bih1, bhh1, out);
    head_kernel<<<TT, 256, 0, stream>>>(embW, indices, Wm, bm, Wv, bv, Wd, bd, out);
}